// Round 11
// baseline (211.214 us; speedup 1.0000x reference)
//
#include <hip/hip_runtime.h>
#include <math.h>

constexpr int B = 8, A = 100000, C = 80, M = 32;
constexpr int APB = 512;                        // anchors per chunk (= block width)
constexpr int CHUNKS = (A + APB - 1) / APB;     // 196 chunks per image
constexpr int CPB = 2;                          // chunks per block
constexpr int NBLK = CHUNKS / CPB;              // 98 blocks per image (exact)
constexpr int C4 = C / 4;                       // 20 float4 per anchor row
constexpr int NWAVE = APB / 64;                 // 8 waves per block
constexpr float NEG_SCALE = 0.75f * 0.6931471805599453f; // 0.75*ln2

__device__ __forceinline__ void f4acc(const float4 v, float& a0, float& a1,
                                      float& a2, float& a3) {
    a0 = fmaf(v.x * v.x, __log2f(1.f - v.x), a0);
    a1 = fmaf(v.y * v.y, __log2f(1.f - v.y), a1);
    a2 = fmaf(v.z * v.z, __log2f(1.f - v.z), a2);
    a3 = fmaf(v.w * v.w, __log2f(1.f - v.w), a3);
}

// d_ws layout: cls_acc[B], reg_acc[B], npos_acc[B]
__global__ __launch_bounds__(512, 4) void focal_main(
    const float* __restrict__ cls,       // [B,A,C]
    const float* __restrict__ regs,      // [B,A,4]
    const float* __restrict__ anchors,   // [1,A,4]
    const float* __restrict__ ann,       // [B,M,5]
    float* __restrict__ cls_acc,
    float* __restrict__ reg_acc,
    unsigned int* __restrict__ npos_acc)
{
    const int b   = blockIdx.y;
    const int tid = threadIdx.x;

    __shared__ float bx1[M], by1[M], bx2[M], by2[M], blab[M], barea[M];
    __shared__ float rc[NWAVE], rr[NWAVE];
    __shared__ int   rp[NWAVE];

    if (tid < M) {
        const float* p = ann + ((size_t)b * M + tid) * 5;
        float x1 = p[0], y1 = p[1], x2 = p[2], y2 = p[3];
        bx1[tid] = x1; by1[tid] = y1; bx2[tid] = x2; by2[tid] = y2;
        blab[tid] = p[4];
        barea[tid] = (x2 - x1) * (y2 - y1);
    }
    __syncthreads();

    float my_cls = 0.f, my_reg = 0.f;    // cls in natural-log loss units
    int   my_pos = 0;

    #pragma unroll 1
    for (int ci = 0; ci < CPB; ++ci) {
        const int a0 = (blockIdx.x * CPB + ci) * APB;
        const int nA = min(APB, A - a0);
        const int a  = a0 + tid;

        // ------------ Phase 1: assignment + corrections (1 thread = 1 anchor)
        float my_corr = 0.f;
        if (tid < nA) {
            float4 ab = *(const float4*)(anchors + (size_t)a * 4);
            const float ax1 = ab.x, ay1 = ab.y, ax2 = ab.z, ay2 = ab.w;
            const float area_a = (ax2 - ax1) * (ay2 - ay1);
            float best = -2.f; int barg = 0;
            #pragma unroll
            for (int m = 0; m < M; ++m) {
                float iw = fminf(ax2, bx2[m]) - fmaxf(ax1, bx1[m]);
                float ih = fminf(ay2, by2[m]) - fmaxf(ay1, by1[m]);
                iw = fmaxf(iw, 0.f); ih = fmaxf(ih, 0.f);
                float inter = iw * ih;
                float ua  = fmaxf(area_a + barea[m] - inter, 1e-8f);
                float iou = inter / ua;
                if (blab[m] == -1.0f) iou = -1.0f;   // invalid annotation mask
                if (iou > best) { best = iou; barg = m; }
            }
            const bool pos = best >= 0.4f;   // IOU_THR + 0.1
            const bool neg = best < 0.3f;    // IOU_THR
            const float* row = cls + ((size_t)b * A + a) * C;
            if (pos) {
                my_pos += 1;
                const int cd = (int)blab[barg];
                float p = row[cd];
                p = fminf(fmaxf(p, 1e-4f), 0.9999f);
                const float omp = 1.f - p;
                // replace streamed neg-term of the target column with pos-term
                my_corr = 0.25f * omp * omp * (-__logf(p))
                        - 0.75f * p * p * (-__logf(omp));
                // regression smooth-L1
                const float aw = ax2 - ax1, ah = ay2 - ay1;
                const float acx = ax1 + 0.5f * aw, acy = ay1 + 0.5f * ah;
                float gw = bx2[barg] - bx1[barg], gh = by2[barg] - by1[barg];
                const float gcx = bx1[barg] + 0.5f * gw, gcy = by1[barg] + 0.5f * gh;
                gw = fmaxf(gw, 1.f); gh = fmaxf(gh, 1.f);
                const float t0 = ((gcx - acx) / aw) / 0.1f;
                const float t1 = ((gcy - acy) / ah) / 0.1f;
                const float t2 = __logf(gw / aw) / 0.2f;
                const float t3 = __logf(gh / ah) / 0.2f;
                float4 rp4 = *(const float4*)(regs + ((size_t)b * A + a) * 4);
                const float d0 = fabsf(t0 - rp4.x), d1 = fabsf(t1 - rp4.y);
                const float d2 = fabsf(t2 - rp4.z), d3 = fabsf(t3 - rp4.w);
                my_reg += (d0 <= 1.f ? 0.5f * d0 * d0 : d0 - 0.5f)
                        + (d1 <= 1.f ? 0.5f * d1 * d1 : d1 - 0.5f)
                        + (d2 <= 1.f ? 0.5f * d2 * d2 : d2 - 0.5f)
                        + (d3 <= 1.f ? 0.5f * d3 * d3 : d3 - 0.5f);
            } else if (!neg) {
                // ignore band: cancel this anchor's whole streamed row
                float c0 = 0.f, c1 = 0.f, c2 = 0.f, c3 = 0.f;
                #pragma unroll 5
                for (int c4i = 0; c4i < C4; ++c4i) {
                    float4 v = *(const float4*)(row + c4i * 4);
                    f4acc(v, c0, c1, c2, c3);
                }
                my_corr = NEG_SCALE * ((c0 + c1) + (c2 + c3)); // subtracts row
            }
        }
        // no __syncthreads(): phases share no LDS state

        // ------------ Phase 2: pure stream, 5 groups x 4 float4, prefetched
        float acc0 = 0.f, acc1 = 0.f, acc2 = 0.f, acc3 = 0.f;  // log2-space
        const float* base = cls + ((size_t)b * A + a0) * C;
        if (nA == APB) {
            const float4* p = (const float4*)base + tid;
            float4 c0 = p[0 * APB];
            float4 c1 = p[1 * APB];
            float4 c2 = p[2 * APB];
            float4 c3 = p[3 * APB];
            #pragma unroll
            for (int g = 0; g < 5; ++g) {
                float4 n0, n1, n2, n3;
                if (g < 4) {
                    const float4* q = p + (g + 1) * 4 * APB;
                    n0 = q[0 * APB];
                    n1 = q[1 * APB];
                    n2 = q[2 * APB];
                    n3 = q[3 * APB];
                }
                f4acc(c0, acc0, acc1, acc2, acc3);
                f4acc(c1, acc0, acc1, acc2, acc3);
                f4acc(c2, acc0, acc1, acc2, acc3);
                f4acc(c3, acc0, acc1, acc2, acc3);
                if (g < 4) { c0 = n0; c1 = n1; c2 = n2; c3 = n3; }
            }
        } else {
            const int n4 = nA * C4;
            for (int i = tid; i < n4; i += APB) {
                float4 v = *(const float4*)(base + (size_t)i * 4);
                f4acc(v, acc0, acc1, acc2, acc3);
            }
        }
        // stream contribution (-NEG_SCALE * S) + this chunk's corrections
        my_cls += fmaf(-NEG_SCALE, (acc0 + acc1) + (acc2 + acc3), my_corr);
    }

    // ---------------- block reduction (8 waves)
    #pragma unroll
    for (int off = 32; off; off >>= 1) {
        my_cls += __shfl_down(my_cls, off);
        my_reg += __shfl_down(my_reg, off);
        my_pos += __shfl_down(my_pos, off);
    }
    const int wid = tid >> 6;
    if ((tid & 63) == 0) { rc[wid] = my_cls; rr[wid] = my_reg; rp[wid] = my_pos; }
    __syncthreads();
    if (tid == 0) {
        float sc = 0.f, sr = 0.f; int sp = 0;
        #pragma unroll
        for (int w = 0; w < NWAVE; ++w) { sc += rc[w]; sr += rr[w]; sp += rp[w]; }
        atomicAdd(&cls_acc[b], sc);
        atomicAdd(&reg_acc[b], sr);
        atomicAdd(&npos_acc[b], (unsigned)sp);
    }
}

__global__ void focal_finalize(const float* __restrict__ cls_acc,
                               const float* __restrict__ reg_acc,
                               const unsigned int* __restrict__ npos_acc,
                               float* __restrict__ out)
{
    if (threadIdx.x == 0) {
        float cm = 0.f, rm = 0.f; unsigned tot = 0u;
        #pragma unroll
        for (int b = 0; b < B; ++b) {
            const unsigned np = npos_acc[b];
            const float npf = (float)np;
            cm += cls_acc[b] / fmaxf(npf, 1.f);
            rm += (np > 0u) ? reg_acc[b] / fmaxf(npf * 4.f, 1.f) : 0.f;
            tot += np;
        }
        out[0] = cm / (float)B;
        out[1] = rm / (float)B;
        out[2] = (float)tot;
    }
}

extern "C" void kernel_launch(void* const* d_in, const int* in_sizes, int n_in,
                              void* d_out, int out_size, void* d_ws, size_t ws_size,
                              hipStream_t stream) {
    const float* cls     = (const float*)d_in[0];
    const float* regs    = (const float*)d_in[1];
    const float* anchors = (const float*)d_in[2];
    const float* ann     = (const float*)d_in[3];
    float* out = (float*)d_out;

    float* cls_acc = (float*)d_ws;
    float* reg_acc = cls_acc + B;
    unsigned int* npos_acc = (unsigned int*)(reg_acc + B);

    hipMemsetAsync(d_ws, 0, 3 * B * sizeof(float), stream);

    dim3 grid(NBLK, B);
    focal_main<<<grid, APB, 0, stream>>>(cls, regs, anchors, ann,
                                         cls_acc, reg_acc, npos_acc);
    focal_finalize<<<1, 64, 0, stream>>>(cls_acc, reg_acc, npos_acc, out);
}

// Round 12
// 76.264 us; speedup vs baseline: 2.7695x; 2.7695x over previous
//
#include <hip/hip_runtime.h>
#include <math.h>

constexpr int B = 8, A = 100000, C = 80, M = 32;
constexpr int APB = 512;                        // anchors per block (512-thread blocks)
constexpr int NBLK = (A + APB - 1) / APB;       // 196 (last block: 160 anchors)
constexpr int C4 = C / 4;                       // 20 float4 per anchor row
constexpr float NEG_SCALE = 0.75f * 0.6931471805599453f; // 0.75*ln2

__device__ __forceinline__ void f4acc(const float4 v, float& a0, float& a1,
                                      float& a2, float& a3) {
    a0 = fmaf(v.x * v.x, __log2f(1.f - v.x), a0);
    a1 = fmaf(v.y * v.y, __log2f(1.f - v.y), a1);
    a2 = fmaf(v.z * v.z, __log2f(1.f - v.z), a2);
    a3 = fmaf(v.w * v.w, __log2f(1.f - v.w), a3);
}

// d_ws layout: cls_acc[B], reg_acc[B], npos_acc[B]
__global__ __launch_bounds__(512, 4) void focal_main(
    const float* __restrict__ cls,       // [B,A,C]
    const float* __restrict__ regs,      // [B,A,4]
    const float* __restrict__ anchors,   // [1,A,4]
    const float* __restrict__ ann,       // [B,M,5]
    float* __restrict__ cls_acc,
    float* __restrict__ reg_acc,
    unsigned int* __restrict__ npos_acc)
{
    const int b   = blockIdx.y;
    const int a0  = blockIdx.x * APB;
    const int tid = threadIdx.x;
    const int nA  = min(APB, A - a0);

    __shared__ float bx1[M], by1[M], bx2[M], by2[M], blab[M], barea[M];
    __shared__ float rc[8], rr[8];
    __shared__ int   rp[8];

    if (tid < M) {
        const float* p = ann + ((size_t)b * M + tid) * 5;
        float x1 = p[0], y1 = p[1], x2 = p[2], y2 = p[3];
        bx1[tid] = x1; by1[tid] = y1; bx2[tid] = x2; by2[tid] = y2;
        blab[tid] = p[4];
        barea[tid] = (x2 - x1) * (y2 - y1);
    }
    __syncthreads();

    // ---------------- Phase 1: assignment + corrections (1 thread = 1 anchor)
    float my_corr = 0.f, my_reg = 0.f;   // my_corr in natural-log loss units
    int   my_pos  = 0;
    const int a = a0 + tid;
    if (tid < nA) {
        float4 ab = *(const float4*)(anchors + (size_t)a * 4);
        const float ax1 = ab.x, ay1 = ab.y, ax2 = ab.z, ay2 = ab.w;
        const float area_a = (ax2 - ax1) * (ay2 - ay1);
        float best = -2.f; int barg = 0;
        #pragma unroll
        for (int m = 0; m < M; ++m) {
            float iw = fminf(ax2, bx2[m]) - fmaxf(ax1, bx1[m]);
            float ih = fminf(ay2, by2[m]) - fmaxf(ay1, by1[m]);
            iw = fmaxf(iw, 0.f); ih = fmaxf(ih, 0.f);
            float inter = iw * ih;
            float ua  = fmaxf(area_a + barea[m] - inter, 1e-8f);
            float iou = inter / ua;
            if (blab[m] == -1.0f) iou = -1.0f;   // invalid annotation mask
            if (iou > best) { best = iou; barg = m; }
        }
        const bool pos = best >= 0.4f;   // IOU_THR + 0.1
        const bool neg = best < 0.3f;    // IOU_THR
        const float* row = cls + ((size_t)b * A + a) * C;
        if (pos) {
            my_pos = 1;
            const int cd = (int)blab[barg];
            float p = row[cd];
            p = fminf(fmaxf(p, 1e-4f), 0.9999f);
            const float omp = 1.f - p;
            // replace the streamed neg-term of the target column with the pos-term
            my_corr = 0.25f * omp * omp * (-__logf(p))
                    - 0.75f * p * p * (-__logf(omp));
            // regression smooth-L1
            const float aw = ax2 - ax1, ah = ay2 - ay1;
            const float acx = ax1 + 0.5f * aw, acy = ay1 + 0.5f * ah;
            float gw = bx2[barg] - bx1[barg], gh = by2[barg] - by1[barg];
            const float gcx = bx1[barg] + 0.5f * gw, gcy = by1[barg] + 0.5f * gh;
            gw = fmaxf(gw, 1.f); gh = fmaxf(gh, 1.f);
            const float t0 = ((gcx - acx) / aw) / 0.1f;
            const float t1 = ((gcy - acy) / ah) / 0.1f;
            const float t2 = __logf(gw / aw) / 0.2f;
            const float t3 = __logf(gh / ah) / 0.2f;
            float4 rp4 = *(const float4*)(regs + ((size_t)b * A + a) * 4);
            const float d0 = fabsf(t0 - rp4.x), d1 = fabsf(t1 - rp4.y);
            const float d2 = fabsf(t2 - rp4.z), d3 = fabsf(t3 - rp4.w);
            my_reg = (d0 <= 1.f ? 0.5f * d0 * d0 : d0 - 0.5f)
                   + (d1 <= 1.f ? 0.5f * d1 * d1 : d1 - 0.5f)
                   + (d2 <= 1.f ? 0.5f * d2 * d2 : d2 - 0.5f)
                   + (d3 <= 1.f ? 0.5f * d3 * d3 : d3 - 0.5f);
        } else if (!neg) {
            // ignore band: cancel this anchor's whole streamed row
            float c0 = 0.f, c1 = 0.f, c2 = 0.f, c3 = 0.f;
            #pragma unroll 5
            for (int c4i = 0; c4i < C4; ++c4i) {
                float4 v = *(const float4*)(row + c4i * 4);
                f4acc(v, c0, c1, c2, c3);
            }
            my_corr = NEG_SCALE * ((c0 + c1) + (c2 + c3)); // subtracts the row
        }
    }
    // no __syncthreads(): phase 2 shares no state with phase 1

    // ---------------- Phase 2: pure stream, 5 groups x 4 float4, prefetched
    float acc0 = 0.f, acc1 = 0.f, acc2 = 0.f, acc3 = 0.f;  // log2-space sums
    const float* base = cls + ((size_t)b * A + a0) * C;
    if (nA == APB) {
        const float4* p = (const float4*)base + tid;
        float4 c0 = p[0 * APB];
        float4 c1 = p[1 * APB];
        float4 c2 = p[2 * APB];
        float4 c3 = p[3 * APB];
        #pragma unroll
        for (int g = 0; g < 5; ++g) {
            float4 n0, n1, n2, n3;
            if (g < 4) {
                const float4* q = p + (g + 1) * 4 * APB;
                n0 = q[0 * APB];
                n1 = q[1 * APB];
                n2 = q[2 * APB];
                n3 = q[3 * APB];
            }
            f4acc(c0, acc0, acc1, acc2, acc3);
            f4acc(c1, acc0, acc1, acc2, acc3);
            f4acc(c2, acc0, acc1, acc2, acc3);
            f4acc(c3, acc0, acc1, acc2, acc3);
            if (g < 4) { c0 = n0; c1 = n1; c2 = n2; c3 = n3; }
        }
    } else {
        const int n4 = nA * C4;
        for (int i = tid; i < n4; i += APB) {
            float4 v = *(const float4*)(base + (size_t)i * 4);
            f4acc(v, acc0, acc1, acc2, acc3);
        }
    }
    // combine: stream contribution (-NEG_SCALE * S) + corrections
    float my_cls = fmaf(-NEG_SCALE, (acc0 + acc1) + (acc2 + acc3), my_corr);

    // ---------------- block reduction (8 waves)
    #pragma unroll
    for (int off = 32; off; off >>= 1) {
        my_cls += __shfl_down(my_cls, off);
        my_reg += __shfl_down(my_reg, off);
        my_pos += __shfl_down(my_pos, off);
    }
    const int wid = tid >> 6;
    if ((tid & 63) == 0) { rc[wid] = my_cls; rr[wid] = my_reg; rp[wid] = my_pos; }
    __syncthreads();
    if (tid == 0) {
        float sc = 0.f, sr = 0.f; int sp = 0;
        #pragma unroll
        for (int w = 0; w < 8; ++w) { sc += rc[w]; sr += rr[w]; sp += rp[w]; }
        atomicAdd(&cls_acc[b], sc);
        atomicAdd(&reg_acc[b], sr);
        atomicAdd(&npos_acc[b], (unsigned)sp);
    }
}

__global__ void focal_finalize(const float* __restrict__ cls_acc,
                               const float* __restrict__ reg_acc,
                               const unsigned int* __restrict__ npos_acc,
                               float* __restrict__ out)
{
    if (threadIdx.x == 0) {
        float cm = 0.f, rm = 0.f; unsigned tot = 0u;
        #pragma unroll
        for (int b = 0; b < B; ++b) {
            const unsigned np = npos_acc[b];
            const float npf = (float)np;
            cm += cls_acc[b] / fmaxf(npf, 1.f);
            rm += (np > 0u) ? reg_acc[b] / fmaxf(npf * 4.f, 1.f) : 0.f;
            tot += np;
        }
        out[0] = cm / (float)B;
        out[1] = rm / (float)B;
        out[2] = (float)tot;
    }
}

extern "C" void kernel_launch(void* const* d_in, const int* in_sizes, int n_in,
                              void* d_out, int out_size, void* d_ws, size_t ws_size,
                              hipStream_t stream) {
    const float* cls     = (const float*)d_in[0];
    const float* regs    = (const float*)d_in[1];
    const float* anchors = (const float*)d_in[2];
    const float* ann     = (const float*)d_in[3];
    float* out = (float*)d_out;

    float* cls_acc = (float*)d_ws;
    float* reg_acc = cls_acc + B;
    unsigned int* npos_acc = (unsigned int*)(reg_acc + B);

    hipMemsetAsync(d_ws, 0, 3 * B * sizeof(float), stream);

    dim3 grid(NBLK, B);
    focal_main<<<grid, APB, 0, stream>>>(cls, regs, anchors, ann,
                                         cls_acc, reg_acc, npos_acc);
    focal_finalize<<<1, 64, 0, stream>>>(cls_acc, reg_acc, npos_acc, out);
}